// Round 1
// baseline (497.332 us; speedup 1.0000x reference)
//
#include <hip/hip_runtime.h>

namespace {

constexpr int B = 2, S = 1024, D = 1024, H = 16, DH = 64;
constexpr int M = B * S;  // 2048 rows
constexpr float EPS = 1e-5f;

__device__ __forceinline__ float wave_sum(float v) {
#pragma unroll
    for (int off = 32; off > 0; off >>= 1) v += __shfl_down(v, off, 64);
    return v;
}
__device__ __forceinline__ float wave_max(float v) {
#pragma unroll
    for (int off = 32; off > 0; off >>= 1) v = fmaxf(v, __shfl_down(v, off, 64));
    return v;
}

// ---------------- Kernel 1: LN(id) -> id_ln ----------------
__global__ __launch_bounds__(256) void ln0_kernel(
    const float* __restrict__ x, const float* __restrict__ g,
    const float* __restrict__ bt, float* __restrict__ y)
{
    __shared__ float sm[8];
    __shared__ float stats[2];
    const int row = blockIdx.x;
    const int t = threadIdx.x;
    const float4 v = reinterpret_cast<const float4*>(x + (size_t)row * D)[t];
    float s  = v.x + v.y + v.z + v.w;
    float ss = v.x*v.x + v.y*v.y + v.z*v.z + v.w*v.w;
    s = wave_sum(s); ss = wave_sum(ss);
    const int lane = t & 63, wid = t >> 6;
    if (lane == 0) { sm[wid] = s; sm[4 + wid] = ss; }
    __syncthreads();
    if (t == 0) {
        float S1 = sm[0] + sm[1] + sm[2] + sm[3];
        float S2 = sm[4] + sm[5] + sm[6] + sm[7];
        float m  = S1 * (1.0f / D);
        float var = S2 * (1.0f / D) - m * m;
        stats[0] = m; stats[1] = rsqrtf(var + EPS);
    }
    __syncthreads();
    const float m = stats[0], r = stats[1];
    const float4 gv = reinterpret_cast<const float4*>(g)[t];
    const float4 bv = reinterpret_cast<const float4*>(bt)[t];
    float4 o;
    o.x = (v.x - m) * r * gv.x + bv.x;
    o.y = (v.y - m) * r * gv.y + bv.y;
    o.z = (v.z - m) * r * gv.z + bv.z;
    o.w = (v.w - m) * r * gv.w + bv.w;
    reinterpret_cast<float4*>(y + (size_t)row * D)[t] = o;
}

// ---------------- Kernel 2: q/k/v = id_ln @ W^T (NT gemm, 64x64 tiles) ----------
__global__ __launch_bounds__(256) void qkv_gemm_kernel(
    const float* __restrict__ A,
    const float* __restrict__ Wq, const float* __restrict__ Wk, const float* __restrict__ Wv,
    float* __restrict__ q, float* __restrict__ k, float* __restrict__ v)
{
    __shared__ float As[16][64];
    __shared__ float Bs[16][64];
    const float* Bm; float* C;
    if (blockIdx.z == 0)      { Bm = Wq; C = q; }
    else if (blockIdx.z == 1) { Bm = Wk; C = k; }
    else                      { Bm = Wv; C = v; }
    const int m0 = blockIdx.y * 64, n0 = blockIdx.x * 64;
    const int t  = threadIdx.x;
    const int tx = t & 15, ty = t >> 4;
    const int lr = t >> 2;         // 0..63
    const int lc = (t & 3) * 4;    // 0,4,8,12
    float acc[4][4] = {};
    for (int k0 = 0; k0 < D; k0 += 16) {
        float4 av = *reinterpret_cast<const float4*>(A  + (size_t)(m0 + lr) * D + k0 + lc);
        float4 bv = *reinterpret_cast<const float4*>(Bm + (size_t)(n0 + lr) * D + k0 + lc);
        __syncthreads();
        As[lc+0][lr] = av.x; As[lc+1][lr] = av.y; As[lc+2][lr] = av.z; As[lc+3][lr] = av.w;
        Bs[lc+0][lr] = bv.x; Bs[lc+1][lr] = bv.y; Bs[lc+2][lr] = bv.z; Bs[lc+3][lr] = bv.w;
        __syncthreads();
#pragma unroll
        for (int kk = 0; kk < 16; ++kk) {
            float a[4], bb[4];
#pragma unroll
            for (int i = 0; i < 4; ++i) a[i]  = As[kk][ty*4 + i];
#pragma unroll
            for (int j = 0; j < 4; ++j) bb[j] = Bs[kk][tx*4 + j];
#pragma unroll
            for (int i = 0; i < 4; ++i)
#pragma unroll
                for (int j = 0; j < 4; ++j)
                    acc[i][j] = fmaf(a[i], bb[j], acc[i][j]);
        }
    }
#pragma unroll
    for (int i = 0; i < 4; ++i) {
        float4 o = make_float4(acc[i][0], acc[i][1], acc[i][2], acc[i][3]);
        *reinterpret_cast<float4*>(C + (size_t)(m0 + ty*4 + i) * D + n0 + tx*4) = o;
    }
}

// ---------------- Kernel 3: scores = q_h @ k_h^T / 8 -> A region --------------
__global__ __launch_bounds__(256) void scores_kernel(
    const float* __restrict__ q, const float* __restrict__ k, float* __restrict__ Aout)
{
    __shared__ float Qs[16][64];
    __shared__ float Ks[16][64];
    const int z = blockIdx.z;          // z = h*B + b
    const int b = z & 1, h = z >> 1;
    const float* qb = q + (size_t)b * S * D + h * DH;
    const float* kb = k + (size_t)b * S * D + h * DH;
    float* Ab = Aout + (size_t)z * S * S;
    const int m0 = blockIdx.y * 64, n0 = blockIdx.x * 64;
    const int t  = threadIdx.x;
    const int tx = t & 15, ty = t >> 4;
    const int lr = t >> 2;
    const int lc = (t & 3) * 4;
    float acc[4][4] = {};
    for (int k0 = 0; k0 < DH; k0 += 16) {
        float4 av = *reinterpret_cast<const float4*>(qb + (size_t)(m0 + lr) * D + k0 + lc);
        float4 bv = *reinterpret_cast<const float4*>(kb + (size_t)(n0 + lr) * D + k0 + lc);
        __syncthreads();
        Qs[lc+0][lr] = av.x; Qs[lc+1][lr] = av.y; Qs[lc+2][lr] = av.z; Qs[lc+3][lr] = av.w;
        Ks[lc+0][lr] = bv.x; Ks[lc+1][lr] = bv.y; Ks[lc+2][lr] = bv.z; Ks[lc+3][lr] = bv.w;
        __syncthreads();
#pragma unroll
        for (int kk = 0; kk < 16; ++kk) {
            float a[4], bb[4];
#pragma unroll
            for (int i = 0; i < 4; ++i) a[i]  = Qs[kk][ty*4 + i];
#pragma unroll
            for (int j = 0; j < 4; ++j) bb[j] = Ks[kk][tx*4 + j];
#pragma unroll
            for (int i = 0; i < 4; ++i)
#pragma unroll
                for (int j = 0; j < 4; ++j)
                    acc[i][j] = fmaf(a[i], bb[j], acc[i][j]);
        }
    }
#pragma unroll
    for (int i = 0; i < 4; ++i) {
        float4 o = make_float4(acc[i][0]*0.125f, acc[i][1]*0.125f,
                               acc[i][2]*0.125f, acc[i][3]*0.125f);
        *reinterpret_cast<float4*>(Ab + (size_t)(m0 + ty*4 + i) * S + n0 + tx*4) = o;
    }
}

// ---------------- Kernel 4: in-place row softmax on A ----------------
__global__ __launch_bounds__(256) void softmax_kernel(float* __restrict__ Aout)
{
    __shared__ float sm[8];
    const size_t row = blockIdx.x;
    float* r = Aout + row * S;
    const int t = threadIdx.x;
    float4 v = reinterpret_cast<float4*>(r)[t];
    float mx = fmaxf(fmaxf(v.x, v.y), fmaxf(v.z, v.w));
    mx = wave_max(mx);
    const int lane = t & 63, wid = t >> 6;
    if (lane == 0) sm[wid] = mx;
    __syncthreads();
    mx = fmaxf(fmaxf(sm[0], sm[1]), fmaxf(sm[2], sm[3]));
    v.x = __expf(v.x - mx); v.y = __expf(v.y - mx);
    v.z = __expf(v.z - mx); v.w = __expf(v.w - mx);
    float s = v.x + v.y + v.z + v.w;
    s = wave_sum(s);
    if (lane == 0) sm[4 + wid] = s;
    __syncthreads();
    s = sm[4] + sm[5] + sm[6] + sm[7];
    const float inv = 1.0f / s;
    v.x *= inv; v.y *= inv; v.z *= inv; v.w *= inv;
    reinterpret_cast<float4*>(r)[t] = v;
}

// ---------------- Kernel 5: O_h = A_h @ v_h ----------------
__global__ __launch_bounds__(256) void ov_kernel(
    const float* __restrict__ Aout, const float* __restrict__ v, float* __restrict__ O)
{
    __shared__ float As[16][64];
    __shared__ float Vs[16][64];
    const int z = blockIdx.z;          // z = h*B + b
    const int b = z & 1, h = z >> 1;
    const float* Ab = Aout + (size_t)z * S * S;
    const float* vb = v + (size_t)b * S * D + h * DH;
    float* Ob = O + (size_t)b * S * D + h * DH;
    const int m0 = blockIdx.y * 64;
    const int t  = threadIdx.x;
    const int tx = t & 15, ty = t >> 4;
    const int lr = t >> 2;
    const int lc = (t & 3) * 4;
    float acc[4][4] = {};
    for (int k0 = 0; k0 < S; k0 += 16) {
        float4 av = *reinterpret_cast<const float4*>(Ab + (size_t)(m0 + lr) * S + k0 + lc);
        float4 vv = *reinterpret_cast<const float4*>(vb + (size_t)(k0 + (t >> 4)) * D + (t & 15) * 4);
        __syncthreads();
        As[lc+0][lr] = av.x; As[lc+1][lr] = av.y; As[lc+2][lr] = av.z; As[lc+3][lr] = av.w;
        *reinterpret_cast<float4*>(&Vs[t >> 4][(t & 15) * 4]) = vv;
        __syncthreads();
#pragma unroll
        for (int kk = 0; kk < 16; ++kk) {
            float a[4], bb[4];
#pragma unroll
            for (int i = 0; i < 4; ++i) a[i]  = As[kk][ty*4 + i];
#pragma unroll
            for (int j = 0; j < 4; ++j) bb[j] = Vs[kk][tx*4 + j];
#pragma unroll
            for (int i = 0; i < 4; ++i)
#pragma unroll
                for (int j = 0; j < 4; ++j)
                    acc[i][j] = fmaf(a[i], bb[j], acc[i][j]);
        }
    }
#pragma unroll
    for (int i = 0; i < 4; ++i) {
        float4 o = make_float4(acc[i][0], acc[i][1], acc[i][2], acc[i][3]);
        *reinterpret_cast<float4*>(Ob + (size_t)(m0 + ty*4 + i) * D + tx*4) = o;
    }
}

// ---------------- Kernel 6: out = LN(id_ln+O,g1,b1) + LN(id+O,g2,b2) ----------
__global__ __launch_bounds__(256) void final_kernel(
    const float* __restrict__ id, const float* __restrict__ id_ln, const float* __restrict__ O,
    const float* __restrict__ g1, const float* __restrict__ b1,
    const float* __restrict__ g2, const float* __restrict__ b2,
    float* __restrict__ out)
{
    __shared__ float sm[16];
    __shared__ float stats[4];
    const int row = blockIdx.x;
    const int t = threadIdx.x;
    const size_t base = (size_t)row * D;
    const float4 xi = reinterpret_cast<const float4*>(id + base)[t];
    const float4 xl = reinterpret_cast<const float4*>(id_ln + base)[t];
    const float4 xo = reinterpret_cast<const float4*>(O + base)[t];
    float4 t1, t2;
    t1.x = xl.x + xo.x; t1.y = xl.y + xo.y; t1.z = xl.z + xo.z; t1.w = xl.w + xo.w;
    t2.x = xi.x + xo.x; t2.y = xi.y + xo.y; t2.z = xi.z + xo.z; t2.w = xi.w + xo.w;
    float s1  = t1.x + t1.y + t1.z + t1.w;
    float ss1 = t1.x*t1.x + t1.y*t1.y + t1.z*t1.z + t1.w*t1.w;
    float s2  = t2.x + t2.y + t2.z + t2.w;
    float ss2 = t2.x*t2.x + t2.y*t2.y + t2.z*t2.z + t2.w*t2.w;
    s1 = wave_sum(s1); ss1 = wave_sum(ss1);
    s2 = wave_sum(s2); ss2 = wave_sum(ss2);
    const int lane = t & 63, wid = t >> 6;
    if (lane == 0) { sm[wid] = s1; sm[4+wid] = ss1; sm[8+wid] = s2; sm[12+wid] = ss2; }
    __syncthreads();
    if (t == 0) {
        float S1 = sm[0]+sm[1]+sm[2]+sm[3];
        float Q1 = sm[4]+sm[5]+sm[6]+sm[7];
        float S2 = sm[8]+sm[9]+sm[10]+sm[11];
        float Q2 = sm[12]+sm[13]+sm[14]+sm[15];
        float m1 = S1 * (1.0f / D);
        float m2 = S2 * (1.0f / D);
        stats[0] = m1; stats[1] = rsqrtf(Q1 * (1.0f / D) - m1*m1 + EPS);
        stats[2] = m2; stats[3] = rsqrtf(Q2 * (1.0f / D) - m2*m2 + EPS);
    }
    __syncthreads();
    const float m1 = stats[0], r1 = stats[1], m2 = stats[2], r2 = stats[3];
    const float4 g1v = reinterpret_cast<const float4*>(g1)[t];
    const float4 b1v = reinterpret_cast<const float4*>(b1)[t];
    const float4 g2v = reinterpret_cast<const float4*>(g2)[t];
    const float4 b2v = reinterpret_cast<const float4*>(b2)[t];
    float4 o;
    o.x = (t1.x - m1)*r1*g1v.x + b1v.x + (t2.x - m2)*r2*g2v.x + b2v.x;
    o.y = (t1.y - m1)*r1*g1v.y + b1v.y + (t2.y - m2)*r2*g2v.y + b2v.y;
    o.z = (t1.z - m1)*r1*g1v.z + b1v.z + (t2.z - m2)*r2*g2v.z + b2v.z;
    o.w = (t1.w - m1)*r1*g1v.w + b1v.w + (t2.w - m2)*r2*g2v.w + b2v.w;
    reinterpret_cast<float4*>(out + base)[t] = o;
}

}  // namespace

extern "C" void kernel_launch(void* const* d_in, const int* in_sizes, int n_in,
                              void* d_out, int out_size, void* d_ws, size_t ws_size,
                              hipStream_t stream)
{
    const float* id = (const float*)d_in[0];
    const float* Wq = (const float*)d_in[1];
    const float* Wk = (const float*)d_in[2];
    const float* Wv = (const float*)d_in[3];
    const float* g0 = (const float*)d_in[4];
    const float* b0 = (const float*)d_in[5];
    const float* g1 = (const float*)d_in[6];
    const float* b1 = (const float*)d_in[7];
    const float* g2 = (const float*)d_in[8];
    const float* b2 = (const float*)d_in[9];

    float* out  = (float*)d_out;
    float* Aout = out + (size_t)B * S * D;          // A region: [H*B, S, S]

    float* ws    = (float*)d_ws;
    const size_t SZ = (size_t)M * D;                // 2 MiB elements
    float* id_ln = ws;
    float* q     = ws + SZ;
    float* k     = ws + 2 * SZ;
    float* v     = ws + 3 * SZ;
    float* O     = ws + 4 * SZ;

    hipLaunchKernelGGL(ln0_kernel, dim3(M), dim3(256), 0, stream, id, g0, b0, id_ln);
    hipLaunchKernelGGL(qkv_gemm_kernel, dim3(D / 64, M / 64, 3), dim3(256), 0, stream,
                       id_ln, Wq, Wk, Wv, q, k, v);
    hipLaunchKernelGGL(scores_kernel, dim3(S / 64, S / 64, B * H), dim3(256), 0, stream,
                       q, k, Aout);
    hipLaunchKernelGGL(softmax_kernel, dim3(H * B * S), dim3(256), 0, stream, Aout);
    hipLaunchKernelGGL(ov_kernel, dim3(1, S / 64, B * H), dim3(256), 0, stream, Aout, v, O);
    hipLaunchKernelGGL(final_kernel, dim3(M), dim3(256), 0, stream,
                       id, id_ln, O, g1, b1, g2, b2, out);
}

// Round 2
// 276.111 us; speedup vs baseline: 1.8012x; 1.8012x over previous
//
#include <hip/hip_runtime.h>

namespace {

constexpr int B = 2, S = 1024, D = 1024, H = 16, DH = 64;
constexpr int M = B * S;  // 2048 rows
constexpr float EPS = 1e-5f;

using bf16x8 = __attribute__((ext_vector_type(8))) short;  // MFMA A/B frag (4 VGPRs)
using f32x4  = __attribute__((ext_vector_type(4))) float;  // MFMA C/D frag

typedef const __attribute__((address_space(1))) void* gptr_t;
typedef __attribute__((address_space(3))) void* lptr_t;

__device__ __forceinline__ unsigned short f2bf(float f) {
    union { float f; unsigned u; } v{f};
    unsigned r = v.u + 0x7fffu + ((v.u >> 16) & 1u);  // RNE
    return (unsigned short)(r >> 16);
}

__device__ __forceinline__ float wave_sum(float v) {
#pragma unroll
    for (int off = 32; off > 0; off >>= 1) v += __shfl_down(v, off, 64);
    return v;
}

// ---------------- Kernel 0: W fp32 -> bf16 ----------------
__global__ __launch_bounds__(256) void cvt_w_kernel(
    const float* __restrict__ Wq, const float* __restrict__ Wk,
    const float* __restrict__ Wv, unsigned short* __restrict__ Wb)
{
    const float* src = (blockIdx.z == 0) ? Wq : (blockIdx.z == 1) ? Wk : Wv;
    const size_t i = ((size_t)blockIdx.x * 256 + threadIdx.x) * 4;
    float4 f = *reinterpret_cast<const float4*>(src + i);
    ushort4 h;
    h.x = f2bf(f.x); h.y = f2bf(f.y); h.z = f2bf(f.z); h.w = f2bf(f.w);
    *reinterpret_cast<ushort4*>(Wb + (size_t)blockIdx.z * D * D + i) = h;
}

// ---------------- Kernel 1: LN(id) -> id_ln (fp32 + bf16) ----------------
__global__ __launch_bounds__(256) void ln0_kernel(
    const float* __restrict__ x, const float* __restrict__ g,
    const float* __restrict__ bt, float* __restrict__ y,
    unsigned short* __restrict__ yb)
{
    __shared__ float sm[8];
    __shared__ float stats[2];
    const int row = blockIdx.x;
    const int t = threadIdx.x;
    const float4 v = reinterpret_cast<const float4*>(x + (size_t)row * D)[t];
    float s  = v.x + v.y + v.z + v.w;
    float ss = v.x*v.x + v.y*v.y + v.z*v.z + v.w*v.w;
    s = wave_sum(s); ss = wave_sum(ss);
    const int lane = t & 63, wid = t >> 6;
    if (lane == 0) { sm[wid] = s; sm[4 + wid] = ss; }
    __syncthreads();
    if (t == 0) {
        float S1 = sm[0] + sm[1] + sm[2] + sm[3];
        float S2 = sm[4] + sm[5] + sm[6] + sm[7];
        float m  = S1 * (1.0f / D);
        float var = S2 * (1.0f / D) - m * m;
        stats[0] = m; stats[1] = rsqrtf(var + EPS);
    }
    __syncthreads();
    const float m = stats[0], r = stats[1];
    const float4 gv = reinterpret_cast<const float4*>(g)[t];
    const float4 bv = reinterpret_cast<const float4*>(bt)[t];
    float4 o;
    o.x = (v.x - m) * r * gv.x + bv.x;
    o.y = (v.y - m) * r * gv.y + bv.y;
    o.z = (v.z - m) * r * gv.z + bv.z;
    o.w = (v.w - m) * r * gv.w + bv.w;
    reinterpret_cast<float4*>(y + (size_t)row * D)[t] = o;
    ushort4 h; h.x = f2bf(o.x); h.y = f2bf(o.y); h.z = f2bf(o.z); h.w = f2bf(o.w);
    *reinterpret_cast<ushort4*>(yb + (size_t)row * D + t * 4) = h;
}

// ---------------- Kernel 2: q/k/v = id_ln @ W^T, bf16 MFMA 128x128 ----------
// z=0 -> q bf16 [M][D]; z=1 -> k bf16 [M][D]; z=2 -> vT bf16 [B][D][S]
__global__ __launch_bounds__(256) void qkv_mfma_kernel(
    const unsigned short* __restrict__ idln, const unsigned short* __restrict__ Wb,
    unsigned short* __restrict__ q, unsigned short* __restrict__ k,
    unsigned short* __restrict__ vT)
{
    __shared__ unsigned short As[128 * 32];
    __shared__ unsigned short Bs[128 * 32];
    const int zi = blockIdx.z;
    const unsigned short* Bmat = Wb + (size_t)zi * D * D;
    const int m0 = blockIdx.y * 128, n0 = blockIdx.x * 128;
    const int t = threadIdx.x;
    const int w = t >> 6, lane = t & 63;
    const int wm = (w >> 1) * 64, wn = (w & 1) * 64;
    const int quad = lane >> 4, l16 = lane & 15;
    const int srow = t >> 2;          // 0..63
    const int scol = (t & 3) * 8;     // 0,8,16,24 (bf16 elems)

    f32x4 acc[4][4];
#pragma unroll
    for (int i = 0; i < 4; ++i)
#pragma unroll
        for (int j = 0; j < 4; ++j) acc[i][j] = (f32x4){0.f, 0.f, 0.f, 0.f};

    for (int k0 = 0; k0 < D; k0 += 32) {
        __syncthreads();
#pragma unroll
        for (int c = 0; c < 2; ++c) {
            const unsigned short* ga = idln + (size_t)(m0 + srow + c * 64) * D + k0 + scol;
            __builtin_amdgcn_global_load_lds((gptr_t)ga, (lptr_t)(As + t * 8 + c * 2048), 16, 0, 0);
            const unsigned short* gb = Bmat + (size_t)(n0 + srow + c * 64) * D + k0 + scol;
            __builtin_amdgcn_global_load_lds((gptr_t)gb, (lptr_t)(Bs + t * 8 + c * 2048), 16, 0, 0);
        }
        __syncthreads();
        bf16x8 af[4], bfr[4];
#pragma unroll
        for (int i = 0; i < 4; ++i)
            af[i] = *reinterpret_cast<const bf16x8*>(As + (wm + i * 16 + l16) * 32 + quad * 8);
#pragma unroll
        for (int j = 0; j < 4; ++j)
            bfr[j] = *reinterpret_cast<const bf16x8*>(Bs + (wn + j * 16 + l16) * 32 + quad * 8);
#pragma unroll
        for (int i = 0; i < 4; ++i)
#pragma unroll
            for (int j = 0; j < 4; ++j)
                acc[i][j] = __builtin_amdgcn_mfma_f32_16x16x32_bf16(af[i], bfr[j], acc[i][j], 0, 0, 0);
    }

    if (zi < 2) {
        unsigned short* C = (zi == 0) ? q : k;
#pragma unroll
        for (int i = 0; i < 4; ++i)
#pragma unroll
            for (int j = 0; j < 4; ++j) {
                const int gcol = n0 + wn + j * 16 + l16;
#pragma unroll
                for (int reg = 0; reg < 4; ++reg) {
                    const int grow = m0 + wm + i * 16 + quad * 4 + reg;
                    C[(size_t)grow * D + gcol] = f2bf(acc[i][j][reg]);
                }
            }
    } else {
        const int b = m0 >> 10;
#pragma unroll
        for (int i = 0; i < 4; ++i)
#pragma unroll
            for (int j = 0; j < 4; ++j) {
                const int gcol = n0 + wn + j * 16 + l16;          // flat D index = h*64+dh
                const int srow0 = (m0 - b * S) + wm + i * 16 + quad * 4;
                ushort4 h;
                h.x = f2bf(acc[i][j][0]); h.y = f2bf(acc[i][j][1]);
                h.z = f2bf(acc[i][j][2]); h.w = f2bf(acc[i][j][3]);
                *reinterpret_cast<ushort4*>(vT + ((size_t)b * D + gcol) * S + srow0) = h;
            }
    }
}

// ---------------- Kernel 3: E = exp(q·k^T/8) fp32 -> A region; row sums ------
__global__ __launch_bounds__(256) void scores_mfma_kernel(
    const unsigned short* __restrict__ q, const unsigned short* __restrict__ k,
    float* __restrict__ Eout, float* __restrict__ rowsum)
{
    __shared__ unsigned short As[128 * 32];
    __shared__ unsigned short Bs[128 * 32];
    const int z = blockIdx.z;            // z = h*B + b
    const int b = z & 1, h = z >> 1;
    const int m0 = blockIdx.y * 128, n0 = blockIdx.x * 128;
    const int t = threadIdx.x;
    const int w = t >> 6, lane = t & 63;
    const int wm = (w >> 1) * 64, wn = (w & 1) * 64;
    const int quad = lane >> 4, l16 = lane & 15;
    const int srow = t >> 2;
    const int scol = (t & 3) * 8;

    f32x4 acc[4][4];
#pragma unroll
    for (int i = 0; i < 4; ++i)
#pragma unroll
        for (int j = 0; j < 4; ++j) acc[i][j] = (f32x4){0.f, 0.f, 0.f, 0.f};

    for (int k0 = 0; k0 < DH; k0 += 32) {
        __syncthreads();
#pragma unroll
        for (int c = 0; c < 2; ++c) {
            const unsigned short* ga = q + (size_t)(b * S + m0 + srow + c * 64) * D + h * DH + k0 + scol;
            __builtin_amdgcn_global_load_lds((gptr_t)ga, (lptr_t)(As + t * 8 + c * 2048), 16, 0, 0);
            const unsigned short* gb = k + (size_t)(b * S + n0 + srow + c * 64) * D + h * DH + k0 + scol;
            __builtin_amdgcn_global_load_lds((gptr_t)gb, (lptr_t)(Bs + t * 8 + c * 2048), 16, 0, 0);
        }
        __syncthreads();
        bf16x8 af[4], bfr[4];
#pragma unroll
        for (int i = 0; i < 4; ++i)
            af[i] = *reinterpret_cast<const bf16x8*>(As + (wm + i * 16 + l16) * 32 + quad * 8);
#pragma unroll
        for (int j = 0; j < 4; ++j)
            bfr[j] = *reinterpret_cast<const bf16x8*>(Bs + (wn + j * 16 + l16) * 32 + quad * 8);
#pragma unroll
        for (int i = 0; i < 4; ++i)
#pragma unroll
            for (int j = 0; j < 4; ++j)
                acc[i][j] = __builtin_amdgcn_mfma_f32_16x16x32_bf16(af[i], bfr[j], acc[i][j], 0, 0, 0);
    }

    float* Ez = Eout + (size_t)z * S * S;
    float part[4][4];   // [i][reg]: per-lane partial row sums over this wave's 64 cols
#pragma unroll
    for (int i = 0; i < 4; ++i)
#pragma unroll
        for (int reg = 0; reg < 4; ++reg) part[i][reg] = 0.f;

#pragma unroll
    for (int i = 0; i < 4; ++i)
#pragma unroll
        for (int j = 0; j < 4; ++j) {
            const int gcol = n0 + wn + j * 16 + l16;
#pragma unroll
            for (int reg = 0; reg < 4; ++reg) {
                const int grow = m0 + wm + i * 16 + quad * 4 + reg;
                float e = __expf(acc[i][j][reg] * 0.125f);
                Ez[(size_t)grow * S + gcol] = e;
                part[i][reg] += e;
            }
        }
    // reduce over the 16 lanes (same quad) holding different cols
#pragma unroll
    for (int i = 0; i < 4; ++i)
#pragma unroll
        for (int reg = 0; reg < 4; ++reg) {
            float p = part[i][reg];
#pragma unroll
            for (int off = 1; off < 16; off <<= 1) p += __shfl_xor(p, off, 64);
            part[i][reg] = p;
        }
    if (l16 == 0) {
#pragma unroll
        for (int i = 0; i < 4; ++i)
#pragma unroll
            for (int reg = 0; reg < 4; ++reg) {
                const int grow = m0 + wm + i * 16 + quad * 4 + reg;
                atomicAdd(&rowsum[(size_t)z * S + grow], part[i][reg]);
            }
    }
}

// ---------------- Kernel 4: O = (E/rowsum)·V; write normalized A in place ----
__global__ __launch_bounds__(256) void ov_mfma_kernel(
    float* __restrict__ Eio, const unsigned short* __restrict__ vT,
    const float* __restrict__ rowsum, float* __restrict__ O)
{
    __shared__ unsigned short Es[128 * 32];
    __shared__ unsigned short Vs[64 * 32];
    __shared__ float sInv[128];
    const int z = blockIdx.z;            // z = h*B + b
    const int b = z & 1, h = z >> 1;
    const int m0 = blockIdx.y * 128;
    const int t = threadIdx.x;
    const int w = t >> 6, lane = t & 63;
    const int wm = w * 32;
    const int quad = lane >> 4, l16 = lane & 15;

    if (t < 128) sInv[t] = 1.0f / rowsum[(size_t)z * S + m0 + t];

    float* Ez = Eio + (size_t)z * S * S;

    f32x4 acc[2][4];
#pragma unroll
    for (int i = 0; i < 2; ++i)
#pragma unroll
        for (int j = 0; j < 4; ++j) acc[i][j] = (f32x4){0.f, 0.f, 0.f, 0.f};

    const int er = t >> 1;               // 0..127
    const int ec = (t & 1) * 16;         // 0 or 16

    for (int k0 = 0; k0 < S; k0 += 32) {
        __syncthreads();
        // stage V^T tile (64 rows x 32 cols bf16) via direct-to-LDS
        {
            const unsigned short* gv = vT + ((size_t)b * D + h * DH + (t >> 2)) * S + k0 + (t & 3) * 8;
            __builtin_amdgcn_global_load_lds((gptr_t)gv, (lptr_t)(Vs + t * 8), 16, 0, 0);
        }
        // stage E tile through registers: convert to bf16, write normalized A in place
        {
            float* gE = Ez + (size_t)(m0 + er) * S + k0 + ec;
            const float inv = sInv[er];
#pragma unroll
            for (int u = 0; u < 4; ++u) {
                float4 f = *reinterpret_cast<const float4*>(gE + u * 4);
                float4 fn = make_float4(f.x * inv, f.y * inv, f.z * inv, f.w * inv);
                *reinterpret_cast<float4*>(gE + u * 4) = fn;
                ushort4 hh;
                hh.x = f2bf(f.x); hh.y = f2bf(f.y); hh.z = f2bf(f.z); hh.w = f2bf(f.w);
                *reinterpret_cast<ushort4*>(Es + er * 32 + ec + u * 4) = hh;
            }
        }
        __syncthreads();
        bf16x8 af[2], bfr[4];
#pragma unroll
        for (int i = 0; i < 2; ++i)
            af[i] = *reinterpret_cast<const bf16x8*>(Es + (wm + i * 16 + l16) * 32 + quad * 8);
#pragma unroll
        for (int j = 0; j < 4; ++j)
            bfr[j] = *reinterpret_cast<const bf16x8*>(Vs + (j * 16 + l16) * 32 + quad * 8);
#pragma unroll
        for (int i = 0; i < 2; ++i)
#pragma unroll
            for (int j = 0; j < 4; ++j)
                acc[i][j] = __builtin_amdgcn_mfma_f32_16x16x32_bf16(af[i], bfr[j], acc[i][j], 0, 0, 0);
    }

#pragma unroll
    for (int i = 0; i < 2; ++i)
#pragma unroll
        for (int j = 0; j < 4; ++j) {
            const int gcol = h * DH + j * 16 + l16;
#pragma unroll
            for (int reg = 0; reg < 4; ++reg) {
                const int lrow = wm + i * 16 + quad * 4 + reg;
                O[(size_t)(b * S + m0 + lrow) * D + gcol] = acc[i][j][reg] * sInv[lrow];
            }
        }
}

// ---------------- Kernel 5: out = LN(id_ln+O,g1,b1) + LN(id+O,g2,b2) ----------
__global__ __launch_bounds__(256) void final_kernel(
    const float* __restrict__ id, const float* __restrict__ id_ln, const float* __restrict__ O,
    const float* __restrict__ g1, const float* __restrict__ b1,
    const float* __restrict__ g2, const float* __restrict__ b2,
    float* __restrict__ out)
{
    __shared__ float sm[16];
    __shared__ float stats[4];
    const int row = blockIdx.x;
    const int t = threadIdx.x;
    const size_t base = (size_t)row * D;
    const float4 xi = reinterpret_cast<const float4*>(id + base)[t];
    const float4 xl = reinterpret_cast<const float4*>(id_ln + base)[t];
    const float4 xo = reinterpret_cast<const float4*>(O + base)[t];
    float4 t1, t2;
    t1.x = xl.x + xo.x; t1.y = xl.y + xo.y; t1.z = xl.z + xo.z; t1.w = xl.w + xo.w;
    t2.x = xi.x + xo.x; t2.y = xi.y + xo.y; t2.z = xi.z + xo.z; t2.w = xi.w + xo.w;
    float s1  = t1.x + t1.y + t1.z + t1.w;
    float ss1 = t1.x*t1.x + t1.y*t1.y + t1.z*t1.z + t1.w*t1.w;
    float s2  = t2.x + t2.y + t2.z + t2.w;
    float ss2 = t2.x*t2.x + t2.y*t2.y + t2.z*t2.z + t2.w*t2.w;
    s1 = wave_sum(s1); ss1 = wave_sum(ss1);
    s2 = wave_sum(s2); ss2 = wave_sum(ss2);
    const int lane = t & 63, wid = t >> 6;
    if (lane == 0) { sm[wid] = s1; sm[4+wid] = ss1; sm[8+wid] = s2; sm[12+wid] = ss2; }
    __syncthreads();
    if (t == 0) {
        float S1 = sm[0]+sm[1]+sm[2]+sm[3];
        float Q1 = sm[4]+sm[5]+sm[6]+sm[7];
        float S2 = sm[8]+sm[9]+sm[10]+sm[11];
        float Q2 = sm[12]+sm[13]+sm[14]+sm[15];
        float m1 = S1 * (1.0f / D);
        float m2 = S2 * (1.0f / D);
        stats[0] = m1; stats[1] = rsqrtf(Q1 * (1.0f / D) - m1*m1 + EPS);
        stats[2] = m2; stats[3] = rsqrtf(Q2 * (1.0f / D) - m2*m2 + EPS);
    }
    __syncthreads();
    const float m1 = stats[0], r1 = stats[1], m2 = stats[2], r2 = stats[3];
    const float4 g1v = reinterpret_cast<const float4*>(g1)[t];
    const float4 b1v = reinterpret_cast<const float4*>(b1)[t];
    const float4 g2v = reinterpret_cast<const float4*>(g2)[t];
    const float4 b2v = reinterpret_cast<const float4*>(b2)[t];
    float4 o;
    o.x = (t1.x - m1)*r1*g1v.x + b1v.x + (t2.x - m2)*r2*g2v.x + b2v.x;
    o.y = (t1.y - m1)*r1*g1v.y + b1v.y + (t2.y - m2)*r2*g2v.y + b2v.y;
    o.z = (t1.z - m1)*r1*g1v.z + b1v.z + (t2.z - m2)*r2*g2v.z + b2v.z;
    o.w = (t1.w - m1)*r1*g1v.w + b1v.w + (t2.w - m2)*r2*g2v.w + b2v.w;
    reinterpret_cast<float4*>(out + base)[t] = o;
}

}  // namespace

extern "C" void kernel_launch(void* const* d_in, const int* in_sizes, int n_in,
                              void* d_out, int out_size, void* d_ws, size_t ws_size,
                              hipStream_t stream)
{
    const float* id = (const float*)d_in[0];
    const float* Wq = (const float*)d_in[1];
    const float* Wk = (const float*)d_in[2];
    const float* Wv = (const float*)d_in[3];
    const float* g0 = (const float*)d_in[4];
    const float* b0 = (const float*)d_in[5];
    const float* g1 = (const float*)d_in[6];
    const float* b1 = (const float*)d_in[7];
    const float* g2 = (const float*)d_in[8];
    const float* b2 = (const float*)d_in[9];

    float* out  = (float*)d_out;
    float* Eout = out + (size_t)B * S * D;   // A region [H*B, S, S] (holds E, then normalized A)

    char* ws = (char*)d_ws;
    float* id_ln  = (float*)(ws);                          //  8 MiB fp32
    float* O      = (float*)(ws + (8u << 20));             //  8 MiB fp32
    float* rowsum = (float*)(ws + (16u << 20));            //  128 KiB fp32
    unsigned short* idln_bf = (unsigned short*)(ws + (16u << 20) + (128u << 10)); // 4 MiB
    unsigned short* Wb      = idln_bf + (size_t)M * D;     //  6 MiB (3 x DxD bf16)
    unsigned short* qb      = Wb + (size_t)3 * D * D;      //  4 MiB
    unsigned short* kb      = qb + (size_t)M * D;          //  4 MiB
    unsigned short* vT      = kb + (size_t)M * D;          //  4 MiB  [B][D][S]

    hipMemsetAsync(rowsum, 0, (size_t)H * B * S * sizeof(float), stream);
    hipLaunchKernelGGL(cvt_w_kernel, dim3(D * D / 1024, 1, 3), dim3(256), 0, stream,
                       Wq, Wk, Wv, Wb);
    hipLaunchKernelGGL(ln0_kernel, dim3(M), dim3(256), 0, stream, id, g0, b0, id_ln, idln_bf);
    hipLaunchKernelGGL(qkv_mfma_kernel, dim3(D / 128, M / 128, 3), dim3(256), 0, stream,
                       idln_bf, Wb, qb, kb, vT);
    hipLaunchKernelGGL(scores_mfma_kernel, dim3(S / 128, S / 128, H * B), dim3(256), 0, stream,
                       qb, kb, Eout, rowsum);
    hipLaunchKernelGGL(ov_mfma_kernel, dim3(1, S / 128, H * B), dim3(256), 0, stream,
                       Eout, vT, rowsum, O);
    hipLaunchKernelGGL(final_kernel, dim3(M), dim3(256), 0, stream,
                       id, id_ln, O, g1, b1, g2, b2, out);
}

// Round 3
// 233.337 us; speedup vs baseline: 2.1314x; 1.1833x over previous
//
#include <hip/hip_runtime.h>

namespace {

constexpr int B = 2, S = 1024, D = 1024, H = 16, DH = 64;
constexpr int M = B * S;  // 2048 rows
constexpr float EPS = 1e-5f;

using bf16x8 = __attribute__((ext_vector_type(8))) short;  // MFMA A/B frag (4 VGPRs)
using f32x4  = __attribute__((ext_vector_type(4))) float;  // MFMA C/D frag

typedef const __attribute__((address_space(1))) void* gptr_t;
typedef __attribute__((address_space(3))) void* lptr_t;

__device__ __forceinline__ unsigned short f2bf(float f) {
    union { float f; unsigned u; } v{f};
    unsigned r = v.u + 0x7fffu + ((v.u >> 16) & 1u);  // RNE
    return (unsigned short)(r >> 16);
}

__device__ __forceinline__ float wave_sum(float v) {
#pragma unroll
    for (int off = 32; off > 0; off >>= 1) v += __shfl_down(v, off, 64);
    return v;
}

// ---------------- Kernel 0: W fp32 -> bf16 ----------------
__global__ __launch_bounds__(256) void cvt_w_kernel(
    const float* __restrict__ Wq, const float* __restrict__ Wk,
    const float* __restrict__ Wv, unsigned short* __restrict__ Wb)
{
    const float* src = (blockIdx.z == 0) ? Wq : (blockIdx.z == 1) ? Wk : Wv;
    const size_t i = ((size_t)blockIdx.x * 256 + threadIdx.x) * 4;
    float4 f = *reinterpret_cast<const float4*>(src + i);
    ushort4 h;
    h.x = f2bf(f.x); h.y = f2bf(f.y); h.z = f2bf(f.z); h.w = f2bf(f.w);
    *reinterpret_cast<ushort4*>(Wb + (size_t)blockIdx.z * D * D + i) = h;
}

// ---------------- Kernel 1: LN(id) -> id_ln (fp32 + bf16) ----------------
__global__ __launch_bounds__(256) void ln0_kernel(
    const float* __restrict__ x, const float* __restrict__ g,
    const float* __restrict__ bt, float* __restrict__ y,
    unsigned short* __restrict__ yb)
{
    __shared__ float sm[8];
    __shared__ float stats[2];
    const int row = blockIdx.x;
    const int t = threadIdx.x;
    const float4 v = reinterpret_cast<const float4*>(x + (size_t)row * D)[t];
    float s  = v.x + v.y + v.z + v.w;
    float ss = v.x*v.x + v.y*v.y + v.z*v.z + v.w*v.w;
    s = wave_sum(s); ss = wave_sum(ss);
    const int lane = t & 63, wid = t >> 6;
    if (lane == 0) { sm[wid] = s; sm[4 + wid] = ss; }
    __syncthreads();
    if (t == 0) {
        float S1 = sm[0] + sm[1] + sm[2] + sm[3];
        float S2 = sm[4] + sm[5] + sm[6] + sm[7];
        float m  = S1 * (1.0f / D);
        float var = S2 * (1.0f / D) - m * m;
        stats[0] = m; stats[1] = rsqrtf(var + EPS);
    }
    __syncthreads();
    const float m = stats[0], r = stats[1];
    const float4 gv = reinterpret_cast<const float4*>(g)[t];
    const float4 bv = reinterpret_cast<const float4*>(bt)[t];
    float4 o;
    o.x = (v.x - m) * r * gv.x + bv.x;
    o.y = (v.y - m) * r * gv.y + bv.y;
    o.z = (v.z - m) * r * gv.z + bv.z;
    o.w = (v.w - m) * r * gv.w + bv.w;
    reinterpret_cast<float4*>(y + (size_t)row * D)[t] = o;
    ushort4 h; h.x = f2bf(o.x); h.y = f2bf(o.y); h.z = f2bf(o.z); h.w = f2bf(o.w);
    *reinterpret_cast<ushort4*>(yb + (size_t)row * D + t * 4) = h;
}

// ---------------- Kernel 2: q/k/v = id_ln @ W^T, bf16 MFMA 128x128 ----------
// z=0 -> q bf16 [M][D]; z=1 -> k bf16 [M][D]; z=2 -> vT bf16 [B][D][S]
__global__ __launch_bounds__(256) void qkv_mfma_kernel(
    const unsigned short* __restrict__ idln, const unsigned short* __restrict__ Wb,
    unsigned short* __restrict__ q, unsigned short* __restrict__ k,
    unsigned short* __restrict__ vT)
{
    __shared__ unsigned short As[128 * 32];
    __shared__ unsigned short Bs[128 * 32];
    const int zi = blockIdx.z;
    const unsigned short* Bmat = Wb + (size_t)zi * D * D;
    const int m0 = blockIdx.y * 128, n0 = blockIdx.x * 128;
    const int t = threadIdx.x;
    const int w = t >> 6, lane = t & 63;
    const int wm = (w >> 1) * 64, wn = (w & 1) * 64;
    const int quad = lane >> 4, l16 = lane & 15;
    const int srow = t >> 2;          // 0..63
    const int scol = (t & 3) * 8;     // 0,8,16,24 (bf16 elems)

    f32x4 acc[4][4];
#pragma unroll
    for (int i = 0; i < 4; ++i)
#pragma unroll
        for (int j = 0; j < 4; ++j) acc[i][j] = (f32x4){0.f, 0.f, 0.f, 0.f};

    for (int k0 = 0; k0 < D; k0 += 32) {
        __syncthreads();
#pragma unroll
        for (int c = 0; c < 2; ++c) {
            const unsigned short* ga = idln + (size_t)(m0 + srow + c * 64) * D + k0 + scol;
            __builtin_amdgcn_global_load_lds((gptr_t)ga, (lptr_t)(As + t * 8 + c * 2048), 16, 0, 0);
            const unsigned short* gb = Bmat + (size_t)(n0 + srow + c * 64) * D + k0 + scol;
            __builtin_amdgcn_global_load_lds((gptr_t)gb, (lptr_t)(Bs + t * 8 + c * 2048), 16, 0, 0);
        }
        __syncthreads();
        bf16x8 af[4], bfr[4];
#pragma unroll
        for (int i = 0; i < 4; ++i)
            af[i] = *reinterpret_cast<const bf16x8*>(As + (wm + i * 16 + l16) * 32 + quad * 8);
#pragma unroll
        for (int j = 0; j < 4; ++j)
            bfr[j] = *reinterpret_cast<const bf16x8*>(Bs + (wn + j * 16 + l16) * 32 + quad * 8);
#pragma unroll
        for (int i = 0; i < 4; ++i)
#pragma unroll
            for (int j = 0; j < 4; ++j)
                acc[i][j] = __builtin_amdgcn_mfma_f32_16x16x32_bf16(af[i], bfr[j], acc[i][j], 0, 0, 0);
    }

    if (zi < 2) {
        unsigned short* C = (zi == 0) ? q : k;
#pragma unroll
        for (int i = 0; i < 4; ++i)
#pragma unroll
            for (int j = 0; j < 4; ++j) {
                const int gcol = n0 + wn + j * 16 + l16;
#pragma unroll
                for (int reg = 0; reg < 4; ++reg) {
                    const int grow = m0 + wm + i * 16 + quad * 4 + reg;
                    C[(size_t)grow * D + gcol] = f2bf(acc[i][j][reg]);
                }
            }
    } else {
        const int b = m0 >> 10;
#pragma unroll
        for (int i = 0; i < 4; ++i)
#pragma unroll
            for (int j = 0; j < 4; ++j) {
                const int gcol = n0 + wn + j * 16 + l16;          // flat D index = h*64+dh
                const int srow0 = (m0 - b * S) + wm + i * 16 + quad * 4;
                ushort4 h;
                h.x = f2bf(acc[i][j][0]); h.y = f2bf(acc[i][j][1]);
                h.z = f2bf(acc[i][j][2]); h.w = f2bf(acc[i][j][3]);
                *reinterpret_cast<ushort4*>(vT + ((size_t)b * D + gcol) * S + srow0) = h;
            }
    }
}

// ------- Kernel 3: fused attention: A = softmax(qk^T/8) (written once), O = A·V -------
// Grid: (1, S/64, H*B). Block 256 = 4 waves. Two passes over key tiles of 128.
__global__ __launch_bounds__(256) void attn_fused_kernel(
    const unsigned short* __restrict__ q, const unsigned short* __restrict__ k,
    const unsigned short* __restrict__ vT, float* __restrict__ Aout,
    float* __restrict__ O)
{
    __shared__ unsigned short Qs[2 * 64 * 32];    // [c_dh][m][32]
    __shared__ unsigned short Ks[2 * 128 * 32];   // [c_dh][n][32]
    __shared__ unsigned short Vs[4 * 64 * 32];    // [kstep][dh][32]  (keys n0+kstep*32..+32)
    __shared__ unsigned short Ps[4 * 64 * 32];    // [kstep][m][32]   (wave w writes slab w)
    __shared__ float rs[4][64];
    __shared__ float sInv[64];

    const int z = blockIdx.z;            // z = h*B + b (head-major A layout)
    const int b = z & 1, h = z >> 1;
    const int m0 = blockIdx.y * 64;
    const int t = threadIdx.x;
    const int w = t >> 6, lane = t & 63;
    const int quad = lane >> 4, l16 = lane & 15;
    const int wn = w * 32;               // wave's key slice within a 128-key tile
    const int sr = t >> 2, sc8 = (t & 3) * 8;

    // stage Q tile (64 x 64) once
#pragma unroll
    for (int c = 0; c < 2; ++c) {
        const unsigned short* gq = q + (size_t)(b * S + m0 + sr) * D + h * DH + c * 32 + sc8;
        __builtin_amdgcn_global_load_lds((gptr_t)gq, (lptr_t)(Qs + c * 2048 + t * 8), 16, 0, 0);
    }

    float part[4][4];
#pragma unroll
    for (int i = 0; i < 4; ++i)
#pragma unroll
        for (int r = 0; r < 4; ++r) part[i][r] = 0.f;

    // ---------------- pass 1: row sums of exp(qk/8) ----------------
    for (int n0 = 0; n0 < S; n0 += 128) {
        __syncthreads();
#pragma unroll
        for (int c = 0; c < 2; ++c)
#pragma unroll
            for (int cc = 0; cc < 2; ++cc) {
                const unsigned short* gk = k + (size_t)(b * S + n0 + cc * 64 + sr) * D + h * DH + c * 32 + sc8;
                __builtin_amdgcn_global_load_lds((gptr_t)gk, (lptr_t)(Ks + c * 4096 + cc * 2048 + t * 8), 16, 0, 0);
            }
        __syncthreads();
        f32x4 acc[4][2];
#pragma unroll
        for (int i = 0; i < 4; ++i)
#pragma unroll
            for (int j = 0; j < 2; ++j) acc[i][j] = (f32x4){0.f, 0.f, 0.f, 0.f};
#pragma unroll
        for (int c = 0; c < 2; ++c) {
            bf16x8 af[4], bfr[2];
#pragma unroll
            for (int i = 0; i < 4; ++i)
                af[i] = *reinterpret_cast<const bf16x8*>(Qs + c * 2048 + (i * 16 + l16) * 32 + quad * 8);
#pragma unroll
            for (int j = 0; j < 2; ++j)
                bfr[j] = *reinterpret_cast<const bf16x8*>(Ks + c * 4096 + (wn + j * 16 + l16) * 32 + quad * 8);
#pragma unroll
            for (int i = 0; i < 4; ++i)
#pragma unroll
                for (int j = 0; j < 2; ++j)
                    acc[i][j] = __builtin_amdgcn_mfma_f32_16x16x32_bf16(af[i], bfr[j], acc[i][j], 0, 0, 0);
        }
#pragma unroll
        for (int i = 0; i < 4; ++i)
#pragma unroll
            for (int j = 0; j < 2; ++j)
#pragma unroll
                for (int r = 0; r < 4; ++r)
                    part[i][r] += __expf(acc[i][j][r] * 0.125f);
    }
    // reduce over the 16 l16 lanes (cols); rows i*16+quad*4+r
#pragma unroll
    for (int i = 0; i < 4; ++i)
#pragma unroll
        for (int r = 0; r < 4; ++r) {
            float p = part[i][r];
#pragma unroll
            for (int off = 1; off < 16; off <<= 1) p += __shfl_xor(p, off, 64);
            if (l16 == 0) rs[w][i * 16 + quad * 4 + r] = p;
        }
    __syncthreads();
    if (t < 64) sInv[t] = 1.0f / (rs[0][t] + rs[1][t] + rs[2][t] + rs[3][t]);

    // ---------------- pass 2: recompute, write A, accumulate O ----------------
    float* Az = Aout + (size_t)z * S * S;
    f32x4 accO[4];
#pragma unroll
    for (int j = 0; j < 4; ++j) accO[j] = (f32x4){0.f, 0.f, 0.f, 0.f};

    for (int n0 = 0; n0 < S; n0 += 128) {
        __syncthreads();
#pragma unroll
        for (int c = 0; c < 2; ++c)
#pragma unroll
            for (int cc = 0; cc < 2; ++cc) {
                const unsigned short* gk = k + (size_t)(b * S + n0 + cc * 64 + sr) * D + h * DH + c * 32 + sc8;
                __builtin_amdgcn_global_load_lds((gptr_t)gk, (lptr_t)(Ks + c * 4096 + cc * 2048 + t * 8), 16, 0, 0);
            }
#pragma unroll
        for (int ks = 0; ks < 4; ++ks) {
            const unsigned short* gv = vT + ((size_t)b * D + h * DH + sr) * S + n0 + ks * 32 + sc8;
            __builtin_amdgcn_global_load_lds((gptr_t)gv, (lptr_t)(Vs + ks * 2048 + t * 8), 16, 0, 0);
        }
        __syncthreads();
        f32x4 acc[4][2];
#pragma unroll
        for (int i = 0; i < 4; ++i)
#pragma unroll
            for (int j = 0; j < 2; ++j) acc[i][j] = (f32x4){0.f, 0.f, 0.f, 0.f};
#pragma unroll
        for (int c = 0; c < 2; ++c) {
            bf16x8 af[4], bfr[2];
#pragma unroll
            for (int i = 0; i < 4; ++i)
                af[i] = *reinterpret_cast<const bf16x8*>(Qs + c * 2048 + (i * 16 + l16) * 32 + quad * 8);
#pragma unroll
            for (int j = 0; j < 2; ++j)
                bfr[j] = *reinterpret_cast<const bf16x8*>(Ks + c * 4096 + (wn + j * 16 + l16) * 32 + quad * 8);
#pragma unroll
            for (int i = 0; i < 4; ++i)
#pragma unroll
                for (int j = 0; j < 2; ++j)
                    acc[i][j] = __builtin_amdgcn_mfma_f32_16x16x32_bf16(af[i], bfr[j], acc[i][j], 0, 0, 0);
        }
        // normalize, write A (final), build P slab (bf16) for this wave's 32 keys
#pragma unroll
        for (int i = 0; i < 4; ++i)
#pragma unroll
            for (int j = 0; j < 2; ++j)
#pragma unroll
                for (int r = 0; r < 4; ++r) {
                    const int rl = i * 16 + quad * 4 + r;
                    float a = __expf(acc[i][j][r] * 0.125f) * sInv[rl];
                    Az[(size_t)(m0 + rl) * S + n0 + wn + j * 16 + l16] = a;
                    Ps[w * 2048 + rl * 32 + j * 16 + l16] = f2bf(a);
                }
        __syncthreads();
        // O += P · V  (K = 128 keys in 4 slabs of 32)
#pragma unroll
        for (int ks = 0; ks < 4; ++ks) {
            bf16x8 af = *reinterpret_cast<const bf16x8*>(Ps + ks * 2048 + (w * 16 + l16) * 32 + quad * 8);
#pragma unroll
            for (int j = 0; j < 4; ++j) {
                bf16x8 bfr = *reinterpret_cast<const bf16x8*>(Vs + ks * 2048 + (j * 16 + l16) * 32 + quad * 8);
                accO[j] = __builtin_amdgcn_mfma_f32_16x16x32_bf16(af, bfr, accO[j], 0, 0, 0);
            }
        }
    }
    // write O (wave w owns rows m0+w*16 .. +15)
#pragma unroll
    for (int j = 0; j < 4; ++j)
#pragma unroll
        for (int r = 0; r < 4; ++r) {
            const int grow = b * S + m0 + w * 16 + quad * 4 + r;
            O[(size_t)grow * D + h * DH + j * 16 + l16] = accO[j][r];
        }
}

// ---------------- Kernel 4: out = LN(id_ln+O,g1,b1) + LN(id+O,g2,b2) ----------
__global__ __launch_bounds__(256) void final_kernel(
    const float* __restrict__ id, const float* __restrict__ id_ln, const float* __restrict__ O,
    const float* __restrict__ g1, const float* __restrict__ b1,
    const float* __restrict__ g2, const float* __restrict__ b2,
    float* __restrict__ out)
{
    __shared__ float sm[16];
    __shared__ float stats[4];
    const int row = blockIdx.x;
    const int t = threadIdx.x;
    const size_t base = (size_t)row * D;
    const float4 xi = reinterpret_cast<const float4*>(id + base)[t];
    const float4 xl = reinterpret_cast<const float4*>(id_ln + base)[t];
    const float4 xo = reinterpret_cast<const float4*>(O + base)[t];
    float4 t1, t2;
    t1.x = xl.x + xo.x; t1.y = xl.y + xo.y; t1.z = xl.z + xo.z; t1.w = xl.w + xo.w;
    t2.x = xi.x + xo.x; t2.y = xi.y + xo.y; t2.z = xi.z + xo.z; t2.w = xi.w + xo.w;
    float s1  = t1.x + t1.y + t1.z + t1.w;
    float ss1 = t1.x*t1.x + t1.y*t1.y + t1.z*t1.z + t1.w*t1.w;
    float s2  = t2.x + t2.y + t2.z + t2.w;
    float ss2 = t2.x*t2.x + t2.y*t2.y + t2.z*t2.z + t2.w*t2.w;
    s1 = wave_sum(s1); ss1 = wave_sum(ss1);
    s2 = wave_sum(s2); ss2 = wave_sum(ss2);
    const int lane = t & 63, wid = t >> 6;
    if (lane == 0) { sm[wid] = s1; sm[4+wid] = ss1; sm[8+wid] = s2; sm[12+wid] = ss2; }
    __syncthreads();
    if (t == 0) {
        float S1 = sm[0]+sm[1]+sm[2]+sm[3];
        float Q1 = sm[4]+sm[5]+sm[6]+sm[7];
        float S2 = sm[8]+sm[9]+sm[10]+sm[11];
        float Q2 = sm[12]+sm[13]+sm[14]+sm[15];
        float m1 = S1 * (1.0f / D);
        float m2 = S2 * (1.0f / D);
        stats[0] = m1; stats[1] = rsqrtf(Q1 * (1.0f / D) - m1*m1 + EPS);
        stats[2] = m2; stats[3] = rsqrtf(Q2 * (1.0f / D) - m2*m2 + EPS);
    }
    __syncthreads();
    const float m1 = stats[0], r1 = stats[1], m2 = stats[2], r2 = stats[3];
    const float4 g1v = reinterpret_cast<const float4*>(g1)[t];
    const float4 b1v = reinterpret_cast<const float4*>(b1)[t];
    const float4 g2v = reinterpret_cast<const float4*>(g2)[t];
    const float4 b2v = reinterpret_cast<const float4*>(b2)[t];
    float4 o;
    o.x = (t1.x - m1)*r1*g1v.x + b1v.x + (t2.x - m2)*r2*g2v.x + b2v.x;
    o.y = (t1.y - m1)*r1*g1v.y + b1v.y + (t2.y - m2)*r2*g2v.y + b2v.y;
    o.z = (t1.z - m1)*r1*g1v.z + b1v.z + (t2.z - m2)*r2*g2v.z + b2v.z;
    o.w = (t1.w - m1)*r1*g1v.w + b1v.w + (t2.w - m2)*r2*g2v.w + b2v.w;
    reinterpret_cast<float4*>(out + base)[t] = o;
}

}  // namespace

extern "C" void kernel_launch(void* const* d_in, const int* in_sizes, int n_in,
                              void* d_out, int out_size, void* d_ws, size_t ws_size,
                              hipStream_t stream)
{
    const float* id = (const float*)d_in[0];
    const float* Wq = (const float*)d_in[1];
    const float* Wk = (const float*)d_in[2];
    const float* Wv = (const float*)d_in[3];
    const float* g0 = (const float*)d_in[4];
    const float* b0 = (const float*)d_in[5];
    const float* g1 = (const float*)d_in[6];
    const float* b1 = (const float*)d_in[7];
    const float* g2 = (const float*)d_in[8];
    const float* b2 = (const float*)d_in[9];

    float* out  = (float*)d_out;
    float* Aout = out + (size_t)B * S * D;   // A region [H*B, S, S], written once by attn

    char* ws = (char*)d_ws;
    float* id_ln  = (float*)(ws);                          //  8 MiB fp32
    float* O      = (float*)(ws + (8u << 20));             //  8 MiB fp32
    unsigned short* idln_bf = (unsigned short*)(ws + (16u << 20)); // 4 MiB
    unsigned short* Wb      = idln_bf + (size_t)M * D;     //  6 MiB (3 x DxD bf16)
    unsigned short* qb      = Wb + (size_t)3 * D * D;      //  4 MiB
    unsigned short* kb      = qb + (size_t)M * D;          //  4 MiB
    unsigned short* vT      = kb + (size_t)M * D;          //  4 MiB  [B][D][S]

    hipLaunchKernelGGL(cvt_w_kernel, dim3(D * D / 1024, 1, 3), dim3(256), 0, stream,
                       Wq, Wk, Wv, Wb);
    hipLaunchKernelGGL(ln0_kernel, dim3(M), dim3(256), 0, stream, id, g0, b0, id_ln, idln_bf);
    hipLaunchKernelGGL(qkv_mfma_kernel, dim3(D / 128, M / 128, 3), dim3(256), 0, stream,
                       idln_bf, Wb, qb, kb, vT);
    hipLaunchKernelGGL(attn_fused_kernel, dim3(1, S / 64, H * B), dim3(256), 0, stream,
                       qb, kb, vT, Aout, O);
    hipLaunchKernelGGL(final_kernel, dim3(M), dim3(256), 0, stream,
                       id, id_ln, O, g1, b1, g2, b2, out);
}

// Round 4
// 233.038 us; speedup vs baseline: 2.1341x; 1.0013x over previous
//
#include <hip/hip_runtime.h>

namespace {

constexpr int B = 2, S = 1024, D = 1024, H = 16, DH = 64;
constexpr int M = B * S;  // 2048 rows
constexpr float EPS = 1e-5f;

using bf16x8 = __attribute__((ext_vector_type(8))) short;  // MFMA A/B frag, K=32 (4 VGPRs)
using bf16x4 = __attribute__((ext_vector_type(4))) short;  // MFMA A/B frag, K=16 (2 VGPRs)
using f32x4  = __attribute__((ext_vector_type(4))) float;  // MFMA C/D frag

typedef const __attribute__((address_space(1))) void* gptr_t;
typedef __attribute__((address_space(3))) void* lptr_t;

__device__ __forceinline__ unsigned short f2bf(float f) {
    union { float f; unsigned u; } v{f};
    unsigned r = v.u + 0x7fffu + ((v.u >> 16) & 1u);  // RNE
    return (unsigned short)(r >> 16);
}

__device__ __forceinline__ float wave_sum(float v) {
#pragma unroll
    for (int off = 32; off > 0; off >>= 1) v += __shfl_down(v, off, 64);
    return v;
}

// ---------------- Kernel 0: W fp32 -> bf16 ----------------
__global__ __launch_bounds__(256) void cvt_w_kernel(
    const float* __restrict__ Wq, const float* __restrict__ Wk,
    const float* __restrict__ Wv, unsigned short* __restrict__ Wb)
{
    const float* src = (blockIdx.z == 0) ? Wq : (blockIdx.z == 1) ? Wk : Wv;
    const size_t i = ((size_t)blockIdx.x * 256 + threadIdx.x) * 4;
    float4 f = *reinterpret_cast<const float4*>(src + i);
    ushort4 h;
    h.x = f2bf(f.x); h.y = f2bf(f.y); h.z = f2bf(f.z); h.w = f2bf(f.w);
    *reinterpret_cast<ushort4*>(Wb + (size_t)blockIdx.z * D * D + i) = h;
}

// ---------------- Kernel 1: LN(id) -> id_ln (fp32 + bf16) ----------------
__global__ __launch_bounds__(256) void ln0_kernel(
    const float* __restrict__ x, const float* __restrict__ g,
    const float* __restrict__ bt, float* __restrict__ y,
    unsigned short* __restrict__ yb)
{
    __shared__ float sm[8];
    __shared__ float stats[2];
    const int row = blockIdx.x;
    const int t = threadIdx.x;
    const float4 v = reinterpret_cast<const float4*>(x + (size_t)row * D)[t];
    float s  = v.x + v.y + v.z + v.w;
    float ss = v.x*v.x + v.y*v.y + v.z*v.z + v.w*v.w;
    s = wave_sum(s); ss = wave_sum(ss);
    const int lane = t & 63, wid = t >> 6;
    if (lane == 0) { sm[wid] = s; sm[4 + wid] = ss; }
    __syncthreads();
    if (t == 0) {
        float S1 = sm[0] + sm[1] + sm[2] + sm[3];
        float S2 = sm[4] + sm[5] + sm[6] + sm[7];
        float m  = S1 * (1.0f / D);
        float var = S2 * (1.0f / D) - m * m;
        stats[0] = m; stats[1] = rsqrtf(var + EPS);
    }
    __syncthreads();
    const float m = stats[0], r = stats[1];
    const float4 gv = reinterpret_cast<const float4*>(g)[t];
    const float4 bv = reinterpret_cast<const float4*>(bt)[t];
    float4 o;
    o.x = (v.x - m) * r * gv.x + bv.x;
    o.y = (v.y - m) * r * gv.y + bv.y;
    o.z = (v.z - m) * r * gv.z + bv.z;
    o.w = (v.w - m) * r * gv.w + bv.w;
    reinterpret_cast<float4*>(y + (size_t)row * D)[t] = o;
    ushort4 h; h.x = f2bf(o.x); h.y = f2bf(o.y); h.z = f2bf(o.z); h.w = f2bf(o.w);
    *reinterpret_cast<ushort4*>(yb + (size_t)row * D + t * 4) = h;
}

// ---------------- Kernel 2: q/k/v = id_ln @ W^T, bf16 MFMA 128x128 ----------
// z=0 -> q bf16 [M][D]; z=1 -> k bf16 [M][D]; z=2 -> vT bf16 [B][D][S]
__global__ __launch_bounds__(256) void qkv_mfma_kernel(
    const unsigned short* __restrict__ idln, const unsigned short* __restrict__ Wb,
    unsigned short* __restrict__ q, unsigned short* __restrict__ k,
    unsigned short* __restrict__ vT)
{
    __shared__ unsigned short As[128 * 32];
    __shared__ unsigned short Bs[128 * 32];
    const int zi = blockIdx.z;
    const unsigned short* Bmat = Wb + (size_t)zi * D * D;
    const int m0 = blockIdx.y * 128, n0 = blockIdx.x * 128;
    const int t = threadIdx.x;
    const int w = t >> 6, lane = t & 63;
    const int wm = (w >> 1) * 64, wn = (w & 1) * 64;
    const int quad = lane >> 4, l16 = lane & 15;
    const int srow = t >> 2;          // 0..63
    const int scol = (t & 3) * 8;     // 0,8,16,24 (bf16 elems)

    f32x4 acc[4][4];
#pragma unroll
    for (int i = 0; i < 4; ++i)
#pragma unroll
        for (int j = 0; j < 4; ++j) acc[i][j] = (f32x4){0.f, 0.f, 0.f, 0.f};

    for (int k0 = 0; k0 < D; k0 += 32) {
        __syncthreads();
#pragma unroll
        for (int c = 0; c < 2; ++c) {
            const unsigned short* ga = idln + (size_t)(m0 + srow + c * 64) * D + k0 + scol;
            __builtin_amdgcn_global_load_lds((gptr_t)ga, (lptr_t)(As + t * 8 + c * 2048), 16, 0, 0);
            const unsigned short* gb = Bmat + (size_t)(n0 + srow + c * 64) * D + k0 + scol;
            __builtin_amdgcn_global_load_lds((gptr_t)gb, (lptr_t)(Bs + t * 8 + c * 2048), 16, 0, 0);
        }
        __syncthreads();
        bf16x8 af[4], bfr[4];
#pragma unroll
        for (int i = 0; i < 4; ++i)
            af[i] = *reinterpret_cast<const bf16x8*>(As + (wm + i * 16 + l16) * 32 + quad * 8);
#pragma unroll
        for (int j = 0; j < 4; ++j)
            bfr[j] = *reinterpret_cast<const bf16x8*>(Bs + (wn + j * 16 + l16) * 32 + quad * 8);
#pragma unroll
        for (int i = 0; i < 4; ++i)
#pragma unroll
            for (int j = 0; j < 4; ++j)
                acc[i][j] = __builtin_amdgcn_mfma_f32_16x16x32_bf16(af[i], bfr[j], acc[i][j], 0, 0, 0);
    }

    if (zi < 2) {
        unsigned short* C = (zi == 0) ? q : k;
#pragma unroll
        for (int i = 0; i < 4; ++i)
#pragma unroll
            for (int j = 0; j < 4; ++j) {
                const int gcol = n0 + wn + j * 16 + l16;
#pragma unroll
                for (int reg = 0; reg < 4; ++reg) {
                    const int grow = m0 + wm + i * 16 + quad * 4 + reg;
                    C[(size_t)grow * D + gcol] = f2bf(acc[i][j][reg]);
                }
            }
    } else {
        const int b = m0 >> 10;
#pragma unroll
        for (int i = 0; i < 4; ++i)
#pragma unroll
            for (int j = 0; j < 4; ++j) {
                const int gcol = n0 + wn + j * 16 + l16;          // flat D index = h*64+dh
                const int srow0 = (m0 - b * S) + wm + i * 16 + quad * 4;
                ushort4 h;
                h.x = f2bf(acc[i][j][0]); h.y = f2bf(acc[i][j][1]);
                h.z = f2bf(acc[i][j][2]); h.w = f2bf(acc[i][j][3]);
                *reinterpret_cast<ushort4*>(vT + ((size_t)b * D + gcol) * S + srow0) = h;
            }
    }
}

// ------- Kernel 3: fused attention v2: S^T orientation, register-P, x16 PV -------
// Grid: (1, S/64, H*B). Block 256 = 4 waves; wave w owns q-rows m0+w*16..+15.
__global__ __launch_bounds__(256) void attn_fused_kernel(
    const unsigned short* __restrict__ q, const unsigned short* __restrict__ k,
    const unsigned short* __restrict__ vT, float* __restrict__ Aout,
    float* __restrict__ O)
{
    __shared__ unsigned short Qs[2 * 64 * 32];   // [c][qrow][32dh]
    __shared__ unsigned short Ks[2 * 64 * 32];   // [c][key][32dh]
    __shared__ unsigned short Vs[4 * 64 * 16];   // [kt][dh][16keys]
    __shared__ float sInv[64];

    const int z = blockIdx.z;            // z = h*B + b (head-major A layout)
    const int b = z & 1, h = z >> 1;
    const int m0 = blockIdx.y * 64;
    const int t = threadIdx.x;
    const int w = t >> 6, lane = t & 63;
    const int quad = lane >> 4, l16 = lane & 15;
    const int sr = t >> 2, sc8 = (t & 3) * 8;

    // stage Q tile (64 x 64) once: two c-slabs of [64][32]
#pragma unroll
    for (int c = 0; c < 2; ++c) {
        const unsigned short* gq = q + (size_t)(b * S + m0 + sr) * D + h * DH + c * 32 + sc8;
        __builtin_amdgcn_global_load_lds((gptr_t)gq, (lptr_t)(Qs + c * 2048 + t * 8), 16, 0, 0);
    }
    __syncthreads();
    // hoist Q B-frags (q = w*16 + l16, dh = c*32 + quad*8..+7)
    bf16x8 qf[2];
#pragma unroll
    for (int c = 0; c < 2; ++c)
        qf[c] = *reinterpret_cast<const bf16x8*>(Qs + c * 2048 + (w * 16 + l16) * 32 + quad * 8);

    // ---------------- pass 1: row sums of exp(qk/8) ----------------
    float rsum = 0.f;
    for (int n0 = 0; n0 < S; n0 += 64) {
        __syncthreads();
#pragma unroll
        for (int c = 0; c < 2; ++c) {
            const unsigned short* gk = k + (size_t)(b * S + n0 + sr) * D + h * DH + c * 32 + sc8;
            __builtin_amdgcn_global_load_lds((gptr_t)gk, (lptr_t)(Ks + c * 2048 + t * 8), 16, 0, 0);
        }
        __syncthreads();
#pragma unroll
        for (int kt = 0; kt < 4; ++kt) {
            f32x4 a = (f32x4){0.f, 0.f, 0.f, 0.f};
#pragma unroll
            for (int c = 0; c < 2; ++c) {
                bf16x8 kf = *reinterpret_cast<const bf16x8*>(Ks + c * 2048 + (kt * 16 + l16) * 32 + quad * 8);
                a = __builtin_amdgcn_mfma_f32_16x16x32_bf16(kf, qf[c], a, 0, 0, 0);
            }
#pragma unroll
            for (int r = 0; r < 4; ++r) rsum += __expf(a[r] * 0.125f);
        }
    }
    rsum += __shfl_xor(rsum, 16, 64);
    rsum += __shfl_xor(rsum, 32, 64);
    if (lane < 16) sInv[w * 16 + lane] = 1.0f / rsum;
    const float sL = 1.0f / rsum;   // every lane has the full sum for q-row l16

    // ---------------- pass 2: recompute, write A (normalized), accumulate O ----
    f32x4 accO[4];
#pragma unroll
    for (int jj = 0; jj < 4; ++jj) accO[jj] = (f32x4){0.f, 0.f, 0.f, 0.f};

    float* Az = Aout + (size_t)z * S * S + (size_t)(m0 + w * 16 + l16) * S;

    for (int n0 = 0; n0 < S; n0 += 64) {
        __syncthreads();
#pragma unroll
        for (int c = 0; c < 2; ++c) {
            const unsigned short* gk = k + (size_t)(b * S + n0 + sr) * D + h * DH + c * 32 + sc8;
            __builtin_amdgcn_global_load_lds((gptr_t)gk, (lptr_t)(Ks + c * 2048 + t * 8), 16, 0, 0);
        }
        // stage V as 4 slabs [kt][dh][16keys]; 2 calls of 2 slabs each
#pragma unroll
        for (int c2 = 0; c2 < 2; ++c2) {
            const int kt = c2 * 2 + (t >> 7);
            const int dh = (t >> 1) & 63;
            const int kh = t & 1;
            const unsigned short* gv = vT + ((size_t)b * D + h * DH + dh) * S + n0 + kt * 16 + kh * 8;
            __builtin_amdgcn_global_load_lds((gptr_t)gv, (lptr_t)(Vs + c2 * 2048 + t * 8), 16, 0, 0);
        }
        __syncthreads();
#pragma unroll
        for (int kt = 0; kt < 4; ++kt) {
            f32x4 a = (f32x4){0.f, 0.f, 0.f, 0.f};
#pragma unroll
            for (int c = 0; c < 2; ++c) {
                bf16x8 kf = *reinterpret_cast<const bf16x8*>(Ks + c * 2048 + (kt * 16 + l16) * 32 + quad * 8);
                a = __builtin_amdgcn_mfma_f32_16x16x32_bf16(kf, qf[c], a, 0, 0, 0);
            }
            float e0 = __expf(a[0] * 0.125f) * sL;
            float e1 = __expf(a[1] * 0.125f) * sL;
            float e2 = __expf(a[2] * 0.125f) * sL;
            float e3 = __expf(a[3] * 0.125f) * sL;
            // write final A: lane's q-row, keys n0+kt*16+quad*4 .. +3 (16B store)
            *reinterpret_cast<float4*>(Az + n0 + kt * 16 + quad * 4) = make_float4(e0, e1, e2, e3);
            // pack P a-frag for x16 MFMA: A[m=q=l16][k=key=quad*4+j]
            bf16x4 p;
            p[0] = (short)f2bf(e0); p[1] = (short)f2bf(e1);
            p[2] = (short)f2bf(e2); p[3] = (short)f2bf(e3);
#pragma unroll
            for (int jj = 0; jj < 4; ++jj) {
                bf16x4 vv = *reinterpret_cast<const bf16x4*>(Vs + kt * 1024 + (jj * 16 + l16) * 16 + quad * 4);
                accO[jj] = __builtin_amdgcn_mfma_f32_16x16x16bf16_1k(p, vv, accO[jj], 0, 0, 0);
            }
        }
    }
    // write O: D row = q = quad*4+r (within wave's 16 rows), col dh = jj*16+l16
#pragma unroll
    for (int jj = 0; jj < 4; ++jj)
#pragma unroll
        for (int r = 0; r < 4; ++r) {
            const int grow = b * S + m0 + w * 16 + quad * 4 + r;
            O[(size_t)grow * D + h * DH + jj * 16 + l16] = accO[jj][r];
        }
}

// ---------------- Kernel 4: out = LN(id_ln+O,g1,b1) + LN(id+O,g2,b2) ----------
__global__ __launch_bounds__(256) void final_kernel(
    const float* __restrict__ id, const float* __restrict__ id_ln, const float* __restrict__ O,
    const float* __restrict__ g1, const float* __restrict__ b1,
    const float* __restrict__ g2, const float* __restrict__ b2,
    float* __restrict__ out)
{
    __shared__ float sm[16];
    __shared__ float stats[4];
    const int row = blockIdx.x;
    const int t = threadIdx.x;
    const size_t base = (size_t)row * D;
    const float4 xi = reinterpret_cast<const float4*>(id + base)[t];
    const float4 xl = reinterpret_cast<const float4*>(id_ln + base)[t];
    const float4 xo = reinterpret_cast<const float4*>(O + base)[t];
    float4 t1, t2;
    t1.x = xl.x + xo.x; t1.y = xl.y + xo.y; t1.z = xl.z + xo.z; t1.w = xl.w + xo.w;
    t2.x = xi.x + xo.x; t2.y = xi.y + xo.y; t2.z = xi.z + xo.z; t2.w = xi.w + xo.w;
    float s1  = t1.x + t1.y + t1.z + t1.w;
    float ss1 = t1.x*t1.x + t1.y*t1.y + t1.z*t1.z + t1.w*t1.w;
    float s2  = t2.x + t2.y + t2.z + t2.w;
    float ss2 = t2.x*t2.x + t2.y*t2.y + t2.z*t2.z + t2.w*t2.w;
    s1 = wave_sum(s1); ss1 = wave_sum(ss1);
    s2 = wave_sum(s2); ss2 = wave_sum(ss2);
    const int lane = t & 63, wid = t >> 6;
    if (lane == 0) { sm[wid] = s1; sm[4+wid] = ss1; sm[8+wid] = s2; sm[12+wid] = ss2; }
    __syncthreads();
    if (t == 0) {
        float S1 = sm[0]+sm[1]+sm[2]+sm[3];
        float Q1 = sm[4]+sm[5]+sm[6]+sm[7];
        float S2 = sm[8]+sm[9]+sm[10]+sm[11];
        float Q2 = sm[12]+sm[13]+sm[14]+sm[15];
        float m1 = S1 * (1.0f / D);
        float m2 = S2 * (1.0f / D);
        stats[0] = m1; stats[1] = rsqrtf(Q1 * (1.0f / D) - m1*m1 + EPS);
        stats[2] = m2; stats[3] = rsqrtf(Q2 * (1.0f / D) - m2*m2 + EPS);
    }
    __syncthreads();
    const float m1 = stats[0], r1 = stats[1], m2 = stats[2], r2 = stats[3];
    const float4 g1v = reinterpret_cast<const float4*>(g1)[t];
    const float4 b1v = reinterpret_cast<const float4*>(b1)[t];
    const float4 g2v = reinterpret_cast<const float4*>(g2)[t];
    const float4 b2v = reinterpret_cast<const float4*>(b2)[t];
    float4 o;
    o.x = (t1.x - m1)*r1*g1v.x + b1v.x + (t2.x - m2)*r2*g2v.x + b2v.x;
    o.y = (t1.y - m1)*r1*g1v.y + b1v.y + (t2.y - m2)*r2*g2v.y + b2v.y;
    o.z = (t1.z - m1)*r1*g1v.z + b1v.z + (t2.z - m2)*r2*g2v.z + b2v.z;
    o.w = (t1.w - m1)*r1*g1v.w + b1v.w + (t2.w - m2)*r2*g2v.w + b2v.w;
    reinterpret_cast<float4*>(out + base)[t] = o;
}

}  // namespace

extern "C" void kernel_launch(void* const* d_in, const int* in_sizes, int n_in,
                              void* d_out, int out_size, void* d_ws, size_t ws_size,
                              hipStream_t stream)
{
    const float* id = (const float*)d_in[0];
    const float* Wq = (const float*)d_in[1];
    const float* Wk = (const float*)d_in[2];
    const float* Wv = (const float*)d_in[3];
    const float* g0 = (const float*)d_in[4];
    const float* b0 = (const float*)d_in[5];
    const float* g1 = (const float*)d_in[6];
    const float* b1 = (const float*)d_in[7];
    const float* g2 = (const float*)d_in[8];
    const float* b2 = (const float*)d_in[9];

    float* out  = (float*)d_out;
    float* Aout = out + (size_t)B * S * D;   // A region [H*B, S, S], written once by attn

    char* ws = (char*)d_ws;
    float* id_ln  = (float*)(ws);                          //  8 MiB fp32
    float* O      = (float*)(ws + (8u << 20));             //  8 MiB fp32
    unsigned short* idln_bf = (unsigned short*)(ws + (16u << 20)); // 4 MiB
    unsigned short* Wb      = idln_bf + (size_t)M * D;     //  6 MiB (3 x DxD bf16)
    unsigned short* qb      = Wb + (size_t)3 * D * D;      //  4 MiB
    unsigned short* kb      = qb + (size_t)M * D;          //  4 MiB
    unsigned short* vT      = kb + (size_t)M * D;          //  4 MiB  [B][D][S]

    hipLaunchKernelGGL(cvt_w_kernel, dim3(D * D / 1024, 1, 3), dim3(256), 0, stream,
                       Wq, Wk, Wv, Wb);
    hipLaunchKernelGGL(ln0_kernel, dim3(M), dim3(256), 0, stream, id, g0, b0, id_ln, idln_bf);
    hipLaunchKernelGGL(qkv_mfma_kernel, dim3(D / 128, M / 128, 3), dim3(256), 0, stream,
                       idln_bf, Wb, qb, kb, vT);
    hipLaunchKernelGGL(attn_fused_kernel, dim3(1, S / 64, H * B), dim3(256), 0, stream,
                       qb, kb, vT, Aout, O);
    hipLaunchKernelGGL(final_kernel, dim3(M), dim3(256), 0, stream,
                       id, id_ln, O, g1, b1, g2, b2, out);
}